// Round 1
// baseline (609.958 us; speedup 1.0000x reference)
//
#include <hip/hip_runtime.h>
#include <math.h>

#define Bn 4
#define Cn 256
#define Vn 512
#define Dn 128
#define NROW (Bn * Vn)       // 2048 (b,v) rows
#define NOUT (Bn * Cn * Vn)  // 524288 output rows of D=128

__device__ __forceinline__ float gelu_exact(float x) {
    return 0.5f * x * (1.0f + erff(x * 0.70710678118654752f));
}

// ---------------------------------------------------------------------------
// Kernel 1: masked mean-pool over C.  One block per (b,v), 128 threads (=d).
// ---------------------------------------------------------------------------
__global__ __launch_bounds__(128) void k1_pool(
    const float* __restrict__ cell, const float* __restrict__ vsm,
    float* __restrict__ pos_emb, float* __restrict__ neg_emb) {
    const int bv = blockIdx.x;
    const int b = bv >> 9;         // / Vn
    const int v = bv & (Vn - 1);
    const int t = threadIdx.x;     // d index
    __shared__ float sp[Cn], sn[Cn];

    for (int c = t; c < Cn; c += 128) {
        sp[c] = vsm[(((size_t)b * 2 + 0) * Cn + c) * Vn + v] > 0.f ? 1.f : 0.f;
        sn[c] = vsm[(((size_t)b * 2 + 1) * Cn + c) * Vn + v] > 0.f ? 1.f : 0.f;
    }
    __syncthreads();

    const float* base = cell + ((size_t)(b * Cn) * Vn + v) * Dn + t;
    float pa = 0.f, na = 0.f, pc = 0.f, nc = 0.f;
#pragma unroll 4
    for (int c = 0; c < Cn; c++) {
        float x = base[(size_t)c * Vn * Dn];
        float p = sp[c], n = sn[c];
        pa += p * x;
        na += n * x;
        pc += p;
        nc += n;
    }
    pos_emb[(size_t)bv * Dn + t] = pa / fmaxf(pc, 1.f);
    neg_emb[(size_t)bv * Dn + t] = na / fmaxf(nc, 1.f);
}

// ---------------------------------------------------------------------------
// Kernel 2: pair_feat build + LN + delta MLP + gate MLP -> pair_delta.
// 256 blocks x 256 threads; each wave privately owns 2 rows (no barriers).
// ---------------------------------------------------------------------------
__global__ __launch_bounds__(256) void k2_mlp(
    const float* __restrict__ pos_emb, const float* __restrict__ neg_emb,
    const int* __restrict__ var_mask,
    const float* __restrict__ pn_g, const float* __restrict__ pn_b,
    const float* __restrict__ dw1, const float* __restrict__ db1,
    const float* __restrict__ dw2, const float* __restrict__ db2,
    const float* __restrict__ gw1, const float* __restrict__ gb1,
    const float* __restrict__ gw2, const float* __restrict__ gb2,
    float* __restrict__ pair_delta) {
    const int w = threadIdx.x >> 6;   // wave 0..3
    const int l = threadIdx.x & 63;   // lane
    __shared__ float pf[8][512];      // normalized pair features
    __shared__ float h1[8][256];      // hidden of delta MLP
    const int r0 = w * 2;                    // local row base (wave-private)
    const int row0 = blockIdx.x * 8 + r0;    // global row = b*Vn + v

    // ---- Phase 0: build pair_feat, LayerNorm(512) in-register, store to LDS
#pragma unroll
    for (int rr = 0; rr < 2; rr++) {
        const int row = row0 + rr;
        const int lr = r0 + rr;
        float2 p2 = *(const float2*)(pos_emb + (size_t)row * Dn + 2 * l);
        float2 n2 = *(const float2*)(neg_emb + (size_t)row * Dn + 2 * l);
        float v0 = p2.x, v1 = p2.y, v2 = n2.x, v3 = n2.y;
        float v4 = v0 - v2, v5 = v1 - v3, v6 = v0 * v2, v7 = v1 * v3;
        float s = v0 + v1 + v2 + v3 + v4 + v5 + v6 + v7;
        float sq = v0 * v0 + v1 * v1 + v2 * v2 + v3 * v3 +
                   v4 * v4 + v5 * v5 + v6 * v6 + v7 * v7;
#pragma unroll
        for (int off = 32; off; off >>= 1) {
            s += __shfl_xor(s, off);
            sq += __shfl_xor(sq, off);
        }
        float m = s * (1.f / 512.f);
        float var = fmaxf(sq * (1.f / 512.f) - m * m, 0.f);
        float rs = rsqrtf(var + 1e-5f);
        float2 ga = *(const float2*)(pn_g + 2 * l);
        float2 gb = *(const float2*)(pn_g + 128 + 2 * l);
        float2 gc = *(const float2*)(pn_g + 256 + 2 * l);
        float2 gd = *(const float2*)(pn_g + 384 + 2 * l);
        float2 ba = *(const float2*)(pn_b + 2 * l);
        float2 bb = *(const float2*)(pn_b + 128 + 2 * l);
        float2 bc = *(const float2*)(pn_b + 256 + 2 * l);
        float2 bd = *(const float2*)(pn_b + 384 + 2 * l);
        *(float2*)&pf[lr][2 * l] =
            make_float2((v0 - m) * rs * ga.x + ba.x, (v1 - m) * rs * ga.y + ba.y);
        *(float2*)&pf[lr][128 + 2 * l] =
            make_float2((v2 - m) * rs * gb.x + bb.x, (v3 - m) * rs * gb.y + bb.y);
        *(float2*)&pf[lr][256 + 2 * l] =
            make_float2((v4 - m) * rs * gc.x + bc.x, (v5 - m) * rs * gc.y + bc.y);
        *(float2*)&pf[lr][384 + 2 * l] =
            make_float2((v6 - m) * rs * gd.x + bd.x, (v7 - m) * rs * gd.y + bd.y);
    }
    // wave-private rows: no __syncthreads needed anywhere.

    // ---- Layer 1: h1 = gelu(pf @ dw1 + db1), lane owns cols 4l..4l+3
    {
        float4 bb4 = *(const float4*)(db1 + 4 * l);
        float acc0[4] = {bb4.x, bb4.y, bb4.z, bb4.w};
        float acc1[4] = {bb4.x, bb4.y, bb4.z, bb4.w};
        for (int k4 = 0; k4 < 128; k4++) {
            float4 a0 = *(const float4*)&pf[r0][4 * k4];
            float4 a1 = *(const float4*)&pf[r0 + 1][4 * k4];
            float a0a[4] = {a0.x, a0.y, a0.z, a0.w};
            float a1a[4] = {a1.x, a1.y, a1.z, a1.w};
            const float* wp = dw1 + (size_t)(4 * k4) * 256 + 4 * l;
#pragma unroll
            for (int q = 0; q < 4; q++) {
                float4 wr = *(const float4*)(wp + (size_t)q * 256);
                acc0[0] += a0a[q] * wr.x; acc0[1] += a0a[q] * wr.y;
                acc0[2] += a0a[q] * wr.z; acc0[3] += a0a[q] * wr.w;
                acc1[0] += a1a[q] * wr.x; acc1[1] += a1a[q] * wr.y;
                acc1[2] += a1a[q] * wr.z; acc1[3] += a1a[q] * wr.w;
            }
        }
        float4 o0 = make_float4(gelu_exact(acc0[0]), gelu_exact(acc0[1]),
                                gelu_exact(acc0[2]), gelu_exact(acc0[3]));
        float4 o1 = make_float4(gelu_exact(acc1[0]), gelu_exact(acc1[1]),
                                gelu_exact(acc1[2]), gelu_exact(acc1[3]));
        *(float4*)&h1[r0][4 * l] = o0;
        *(float4*)&h1[r0 + 1][4 * l] = o1;
    }

    // ---- Layer 2: h2 = h1 @ dw2 + db2, lane owns cols 2l, 2l+1
    float h2[2][2];
    {
        float2 bb2 = *(const float2*)(db2 + 2 * l);
        float a20[2] = {bb2.x, bb2.y};
        float a21[2] = {bb2.x, bb2.y};
        for (int k4 = 0; k4 < 64; k4++) {
            float4 a0 = *(const float4*)&h1[r0][4 * k4];
            float4 a1 = *(const float4*)&h1[r0 + 1][4 * k4];
            float a0a[4] = {a0.x, a0.y, a0.z, a0.w};
            float a1a[4] = {a1.x, a1.y, a1.z, a1.w};
            const float* wp = dw2 + (size_t)(4 * k4) * 128 + 2 * l;
#pragma unroll
            for (int q = 0; q < 4; q++) {
                float2 wr = *(const float2*)(wp + (size_t)q * 128);
                a20[0] += a0a[q] * wr.x; a20[1] += a0a[q] * wr.y;
                a21[0] += a1a[q] * wr.x; a21[1] += a1a[q] * wr.y;
            }
        }
        h2[0][0] = a20[0]; h2[0][1] = a20[1];
        h2[1][0] = a21[0]; h2[1][1] = a21[1];
    }

    // ---- Gate MLP: gelu(pf @ gw1 + gb1) col l, then sigmoid(. @ gw2 + gb2)
    float gate[2];
    {
        float hg0 = gb1[l], hg1 = gb1[l];
        for (int k4 = 0; k4 < 128; k4++) {
            float4 a0 = *(const float4*)&pf[r0][4 * k4];
            float4 a1 = *(const float4*)&pf[r0 + 1][4 * k4];
            float a0a[4] = {a0.x, a0.y, a0.z, a0.w};
            float a1a[4] = {a1.x, a1.y, a1.z, a1.w};
            const float* wp = gw1 + (size_t)(4 * k4) * 64 + l;
#pragma unroll
            for (int q = 0; q < 4; q++) {
                float wq = wp[(size_t)q * 64];
                hg0 += a0a[q] * wq;
                hg1 += a1a[q] * wq;
            }
        }
        hg0 = gelu_exact(hg0);
        hg1 = gelu_exact(hg1);
        float w2 = gw2[l];
        float s0 = hg0 * w2, s1 = hg1 * w2;
#pragma unroll
        for (int off = 32; off; off >>= 1) {
            s0 += __shfl_xor(s0, off);
            s1 += __shfl_xor(s1, off);
        }
        float bb = gb2[0];
        gate[0] = 1.f / (1.f + expf(-(s0 + bb)));
        gate[1] = 1.f / (1.f + expf(-(s1 + bb)));
    }

    // ---- Apply gate + var_mask, write pair_delta
#pragma unroll
    for (int rr = 0; rr < 2; rr++) {
        const int row = row0 + rr;
        float vm = (var_mask[row] != 0) ? 1.f : 0.f;
        float sc = gate[rr] * vm;
        float2 o = make_float2(h2[rr][0] * sc, h2[rr][1] * sc);
        *(float2*)(pair_delta + (size_t)row * Dn + 2 * l) = o;
    }
}

// ---------------------------------------------------------------------------
// Kernel 3: out = LayerNorm_D(cell + 0.1*sign*pair_delta).  One wave per row.
// ---------------------------------------------------------------------------
__global__ __launch_bounds__(256) void k3_out(
    const float* __restrict__ cell, const float* __restrict__ vsm,
    const float* __restrict__ pair_delta,
    const float* __restrict__ on_g, const float* __restrict__ on_b,
    float* __restrict__ out) {
    const int l = threadIdx.x & 63;
    int wave = blockIdx.x * 4 + (threadIdx.x >> 6);
    const int nw = gridDim.x * 4;
    float2 g2 = *(const float2*)(on_g + 2 * l);
    float2 b2 = *(const float2*)(on_b + 2 * l);
    for (int row = wave; row < NOUT; row += nw) {
        const int v = row & (Vn - 1);
        const int bc = row >> 9;
        const int b = bc >> 8;
        const int c = bc & (Cn - 1);
        float sp = vsm[(((size_t)b * 2 + 0) * Cn + c) * Vn + v];
        float sn = vsm[(((size_t)b * 2 + 1) * Cn + c) * Vn + v];
        float sgn = 0.1f * ((sp > 0.f ? 1.f : 0.f) - (sn > 0.f ? 1.f : 0.f));
        float2 ce = *(const float2*)(cell + (size_t)row * Dn + 2 * l);
        float2 pd = *(const float2*)(pair_delta + ((size_t)(b * Vn + v)) * Dn + 2 * l);
        float x0 = fmaf(sgn, pd.x, ce.x);
        float x1 = fmaf(sgn, pd.y, ce.y);
        float s = x0 + x1, sq = x0 * x0 + x1 * x1;
#pragma unroll
        for (int off = 32; off; off >>= 1) {
            s += __shfl_xor(s, off);
            sq += __shfl_xor(sq, off);
        }
        float m = s * (1.f / 128.f);
        float var = fmaxf(sq * (1.f / 128.f) - m * m, 0.f);
        float rs = rsqrtf(var + 1e-5f);
        float2 o = make_float2((x0 - m) * rs * g2.x + b2.x,
                               (x1 - m) * rs * g2.y + b2.y);
        *(float2*)(out + (size_t)row * Dn + 2 * l) = o;
    }
}

// ---------------------------------------------------------------------------
extern "C" void kernel_launch(void* const* d_in, const int* in_sizes, int n_in,
                              void* d_out, int out_size, void* d_ws, size_t ws_size,
                              hipStream_t stream) {
    const float* cell  = (const float*)d_in[0];
    const float* vsm   = (const float*)d_in[1];
    const int*   vmask = (const int*)d_in[2];   // jax bool -> int32 per harness
    const float* pn_g  = (const float*)d_in[3];
    const float* pn_b  = (const float*)d_in[4];
    const float* dw1   = (const float*)d_in[5];
    const float* db1   = (const float*)d_in[6];
    const float* dw2   = (const float*)d_in[7];
    const float* db2   = (const float*)d_in[8];
    const float* gw1   = (const float*)d_in[9];
    const float* gb1   = (const float*)d_in[10];
    const float* gw2   = (const float*)d_in[11];
    const float* gb2   = (const float*)d_in[12];
    const float* on_g  = (const float*)d_in[13];
    const float* on_b  = (const float*)d_in[14];
    float* out = (float*)d_out;

    float* pos    = (float*)d_ws;                    // [NROW, Dn]  1 MB
    float* neg    = pos + (size_t)NROW * Dn;         // [NROW, Dn]  1 MB
    float* pdelta = neg + (size_t)NROW * Dn;         // [NROW, Dn]  1 MB

    hipLaunchKernelGGL(k1_pool, dim3(NROW), dim3(128), 0, stream,
                       cell, vsm, pos, neg);
    hipLaunchKernelGGL(k2_mlp, dim3(NROW / 8), dim3(256), 0, stream,
                       pos, neg, vmask, pn_g, pn_b, dw1, db1, dw2, db2,
                       gw1, gb1, gw2, gb2, pdelta);
    hipLaunchKernelGGL(k3_out, dim3(2048), dim3(256), 0, stream,
                       cell, vsm, pdelta, on_g, on_b, out);
}